// Round 19
// baseline (243.296 us; speedup 1.0000x reference)
//
#include <hip/hip_runtime.h>
#include <hip/hip_bf16.h>
#include <stdint.h>

typedef unsigned short u16;
typedef float f4v __attribute__((ext_vector_type(4)));
typedef short s8v __attribute__((ext_vector_type(8)));

// B=32, T=64, N=2048, HID=256, HEADS=8, DH=32, BOT=64, MAX_LAG=7 ; rows = 65536

__device__ __forceinline__ float bf2f(u16 u) {
  union { float f; uint32_t i; } x; x.i = ((uint32_t)u) << 16; return x.f;
}
__device__ __forceinline__ u16 f2bf(float f) {
  uint32_t u = __float_as_uint(f);
  u = (u + 0x7FFFu + ((u >> 16) & 1u)) >> 16;
  return (u16)u;
}
__device__ __forceinline__ uint32_t pk2(float a, float b) {
  return (uint32_t)f2bf(a) | ((uint32_t)f2bf(b) << 16);
}
__device__ __forceinline__ void gload16(const void* g, void* l) {
  __builtin_amdgcn_global_load_lds((const __attribute__((address_space(1))) void*)g,
                                   (__attribute__((address_space(3))) void*)l, 16, 0, 0);
}

// ---------------- prep_all: delayed + weight transposes + folded delay weights ----------------
__global__ __launch_bounds__(256) void prep_all_k(
    const float* __restrict__ x, const float* __restrict__ dlog,
    const float* __restrict__ w_dp, const float* __restrict__ b_dp,
    const float* __restrict__ wql, const float* __restrict__ bql,
    const float* __restrict__ wqh, const float* __restrict__ wol,
    const float* __restrict__ bqh,
    float* __restrict__ wl_d, float* __restrict__ bl_p, float* __restrict__ delayed,
    u16* __restrict__ wqlT, u16* __restrict__ wqhT, u16* __restrict__ wvlT,
    float* __restrict__ cvl) {
  const int bid = blockIdx.x, t = threadIdx.x;
  if (bid < 256) {
    float mx = dlog[0];
#pragma unroll
    for (int i = 1; i < 8; ++i) mx = fmaxf(mx, dlog[i]);
    float w8[8], ssum = 0.f;
#pragma unroll
    for (int i = 0; i < 8; ++i) { w8[i] = __expf(dlog[i] - mx); ssum += w8[i]; }
    float inv = 1.f / ssum;
    int r = bid * 256 + t;
    int b = r >> 11, n = r & 2047;
    const float* xb = x + (size_t)b * 64 * 2048;
    float acc = 0.f;
#pragma unroll
    for (int tau = 0; tau < 8; ++tau) acc += w8[tau] * inv * xb[(size_t)(63 - tau) * 2048 + n];
    delayed[r] = acc;
  } else if (bid < 512) {
    int n = bid - 256;
    wqlT[(size_t)n * 256 + t] = f2bf(n < 192 ? wql[(size_t)t * 192 + n] : 0.f);
  } else if (bid < 1280) {
    int n = bid - 512;
    if (t < 192) wqhT[(size_t)n * 192 + t] = f2bf(wqh[(size_t)t * 768 + n]);
  } else if (bid < 1408) {
    int d = bid - 1280;   // 0..127 (pad to 128)
    __shared__ float wolc[256];
    if (d < 64) wolc[t] = wol[(size_t)t * 64 + d];
    __syncthreads();
    if (t < 192) {
      float s = 0.f;
      if (d < 64) {
        const float* wr = wqh + (size_t)t * 768 + 512;
        for (int c = 0; c < 256; ++c) s = fmaf(wr[c], wolc[c], s);
      }
      wvlT[(size_t)d * 192 + t] = f2bf(s);
    }
    if (t == 0 && d < 64) {
      float s = 0.f;
      for (int c = 0; c < 256; ++c) s = fmaf(bqh[512 + c], wolc[c], s);
      cvl[d] = s;
    }
  } else {
    if (t < 192) {
      float s1 = 0.f, s2 = 0.f;
      for (int k = 0; k < 256; ++k) {
        float w = wql[k * 192 + t];
        s1 += w_dp[k] * w;
        s2 += b_dp[k] * w;
      }
      wl_d[t] = 0.1f * s1;
      bl_p[t] = bql[t] + 0.1f * s2;
    }
  }
}

// ---------------- adj fp32 -> bf16 ----------------
__global__ __launch_bounds__(256) void cvtadj_k(const float* __restrict__ in,
                                                u16* __restrict__ out) {
  size_t i = ((size_t)blockIdx.x * 256 + threadIdx.x) * 8;
  float4 a = *(const float4*)(in + i);
  float4 b = *(const float4*)(in + i + 4);
  uint4 q = {pk2(a.x, a.y), pk2(a.z, a.w), pk2(b.x, b.y), pk2(b.z, b.w)};
  *(uint4*)(out + i) = q;
}

// ---------------- bf16 MFMA GEMM template (128x128 tile, BK=64, 4 waves) ----------------
struct MArgs {
  const u16* A;        // GQ/GVP: low
  const float* Af32;   // GLOW: features (fp32, reg-staged)
  const u16* adjb;     // GGEO: adj bf16 (gload16)
  const u16* Bt;
  const float* delayed; const float* wl_d; const float* bl_p;   // GLOW
  const float* bqh;                                             // GQ
  const float* cvl;                                             // GVP
  const float* kspart;                                          // GQ (fused rden scale)
  u16* low; u16* qf; u16* vpt;                                  // qf = PRE-SCALED qs
  u16* geopart;        // GGEO split-K partials
};

enum { GLOW = 0, GQ = 1, GGEO = 2, GVP = 3 };

template <int MODE>
__global__ __launch_bounds__(256) void mgemm_k(MArgs ma) {
  constexpr int KLOOP = (MODE == GLOW) ? 256 : (MODE == GGEO) ? 512 : 192;
  constexpr int LDA = (MODE == GLOW) ? 256 : (MODE == GGEO) ? 2048 : 192;
  constexpr int LDB = (MODE == GLOW) ? 256 : (MODE == GGEO) ? 2048 : 192;
  constexpr bool SWAPPED = (MODE != GVP);

  __shared__ __align__(16) u16 SH[128 * 128];
  u16* Al = SH;
  u16* Bl = SH + 128 * 64;

  const int t = threadIdx.x;
  const int l = t & 63, w = t >> 6;
  const int wm = w >> 1, wn = w & 1;

  // XCD-aware (ct,rt): colocate blocks sharing an A panel on one XCD
  int ct, rt, bz = 0;
  if constexpr (MODE == GGEO) {
    int lin = blockIdx.x + 16 * blockIdx.y + 256 * blockIdx.z;
    int xcd = lin & 7, idx = lin >> 3;
    ct = idx & 15;
    int pid = xcd * 8 + (idx >> 4);   // 0..63
    rt = pid & 15;
    bz = pid >> 4;                    // 0..3
  } else {
    constexpr int NCT = (MODE == GVP) ? 1 : 2;
    int lin = blockIdx.x + NCT * blockIdx.y;
    int xcd = lin & 7, idx = lin >> 3;
    ct = idx % NCT; rt = xcd * 64 + idx / NCT;
  }
  const int kbase = (MODE == GGEO) ? bz * 512 : 0;

  f4v acc[4][4] = {};

  for (int k0 = 0; k0 < KLOOP; k0 += 64) {
    __syncthreads();
#pragma unroll
    for (int s = 0; s < 4; ++s) {
      int c = s * 256 + t;                 // 0..1023
      int r = c >> 3, cc = c & 7;
      int g = ((cc & 3) ^ ((r >> 1) & 3)) | ((cc & 4) ^ ((r & 1) << 2));
      int row = rt * 128 + r;
      int kg = kbase + k0 + g * 8;
      if constexpr (MODE == GLOW) {
        const float* src = ma.Af32 + (size_t)row * LDA + kg;
        float4 x0 = *(const float4*)src;
        float4 x1 = *(const float4*)(src + 4);
        uint4 qq = {pk2(x0.x, x0.y), pk2(x0.z, x0.w), pk2(x1.x, x1.y), pk2(x1.z, x1.w)};
        *(uint4*)&Al[c * 8] = qq;
      } else if constexpr (MODE == GGEO) {
        gload16(ma.adjb + (size_t)row * 2048 + kg, (char*)Al + (s * 4 + w) * 1024);
      } else {
        gload16(ma.A + (size_t)row * LDA + kg, (char*)Al + (s * 4 + w) * 1024);
      }
      gload16(ma.Bt + (size_t)(ct * 128 + r) * LDB + kg,
              (char*)Bl + (s * 4 + w) * 1024);
    }
    __syncthreads();

#pragma unroll
    for (int kk = 0; kk < 64; kk += 32) {
      s8v fa[4], fb[4];
#pragma unroll
      for (int mr = 0; mr < 4; ++mr) {
        int ra = wm * 64 + mr * 16 + (l & 15);
        int ch = ((l >> 4) ^ ((ra >> 1) & 3)) | ((kk >> 3) ^ ((ra & 1) << 2));
        fa[mr] = *(const s8v*)(Al + ra * 64 + ch * 8);
      }
#pragma unroll
      for (int nr = 0; nr < 4; ++nr) {
        int rb = wn * 64 + nr * 16 + (l & 15);
        int cb = ((l >> 4) ^ ((rb >> 1) & 3)) | ((kk >> 3) ^ ((rb & 1) << 2));
        fb[nr] = *(const s8v*)(Bl + rb * 64 + cb * 8);
      }
      if constexpr (SWAPPED) {
#pragma unroll
        for (int mr = 0; mr < 4; ++mr)
#pragma unroll
          for (int nr = 0; nr < 4; ++nr)
            acc[mr][nr] = __builtin_amdgcn_mfma_f32_16x16x32_bf16(fb[nr], fa[mr], acc[mr][nr], 0, 0, 0);
      } else {
#pragma unroll
        for (int mr = 0; mr < 4; ++mr)
#pragma unroll
          for (int nr = 0; nr < 4; ++nr)
            acc[mr][nr] = __builtin_amdgcn_mfma_f32_16x16x32_bf16(fa[mr], fb[nr], acc[mr][nr], 0, 0, 0);
      }
    }
  }

  const int r0 = rt * 128 + wm * 64, c0 = ct * 128 + wn * 64;

  if constexpr (MODE == GVP) {
    const int lr = (l >> 4) * 4, lc = l & 15;
#pragma unroll
    for (int mr = 0; mr < 4; ++mr)
#pragma unroll
      for (int nr = 0; nr < 4; ++nr) {
        if (wn == 0) {
          int d = nr * 16 + lc;
          float cadd = ma.cvl[d];
          int n0 = (r0 + mr * 16 + lr) & 2047;
          int b = rt >> 4;
          ushort4 st = {f2bf(acc[mr][nr][0] + cadd), f2bf(acc[mr][nr][1] + cadd),
                        f2bf(acc[mr][nr][2] + cadd), f2bf(acc[mr][nr][3] + cadd)};
          *(ushort4*)(ma.vpt + ((size_t)(b * 64 + d)) * 2048 + n0) = st;
        }
      }
  } else if constexpr (MODE == GQ) {
    // ---- ksumf into aliased LDS (staging done) ----
    __syncthreads();
    float* ksumf = (float*)SH;
    {
      int bb = rt >> 4;
      float s = 0.f;
#pragma unroll
      for (int p = 0; p < 16; ++p)
        s += ma.kspart[(size_t)(p * 256 + bb * 8 + (t >> 5)) * 32 + (t & 31)];
      ksumf[t] = s + 1e-8f;
    }
    __syncthreads();
    const int rowl = l & 15, colq = (l >> 4) * 4;
    float dp[4][2] = {};
    // pass 1: bias + elu, bf16-round into acc, accumulate den partials
#pragma unroll
    for (int mr = 0; mr < 4; ++mr) {
#pragma unroll
      for (int nr = 0; nr < 4; ++nr) {
        int col0 = c0 + nr * 16 + colq;
        float4 bias = *(const float4*)(ma.bqh + col0);
        float v0 = acc[mr][nr][0] + bias.x;
        float v1 = acc[mr][nr][1] + bias.y;
        float v2 = acc[mr][nr][2] + bias.z;
        float v3 = acc[mr][nr][3] + bias.w;
        v0 = (v0 > 0.f) ? (v0 + 1.f) : __expf(v0);
        v1 = (v1 > 0.f) ? (v1 + 1.f) : __expf(v1);
        v2 = (v2 > 0.f) ? (v2 + 1.f) : __expf(v2);
        v3 = (v3 > 0.f) ? (v3 + 1.f) : __expf(v3);
        float r0f = bf2f(f2bf(v0)), r1f = bf2f(f2bf(v1));
        float r2f = bf2f(f2bf(v2)), r3f = bf2f(f2bf(v3));
        f4v rr = {r0f, r1f, r2f, r3f};
        acc[mr][nr] = rr;
        dp[mr][nr >> 1] += r0f * ksumf[col0] + r1f * ksumf[col0 + 1] +
                           r2f * ksumf[col0 + 2] + r3f * ksumf[col0 + 3];
      }
    }
    // butterfly: all 4 lanes sharing (rowl, head) get the full den
#pragma unroll
    for (int mr = 0; mr < 4; ++mr)
#pragma unroll
      for (int g = 0; g < 2; ++g) {
        dp[mr][g] += __shfl_xor(dp[mr][g], 16);
        dp[mr][g] += __shfl_xor(dp[mr][g], 32);
      }
    // pass 2: scale by 1/den, store pre-scaled qs
#pragma unroll
    for (int mr = 0; mr < 4; ++mr) {
      int row = r0 + mr * 16 + rowl;
#pragma unroll
      for (int nr = 0; nr < 4; ++nr) {
        int col0 = c0 + nr * 16 + colq;
        float rd = 1.f / (dp[mr][nr >> 1] + 1e-8f);
        ushort4 st = {f2bf(acc[mr][nr][0] * rd), f2bf(acc[mr][nr][1] * rd),
                      f2bf(acc[mr][nr][2] * rd), f2bf(acc[mr][nr][3] * rd)};
        *(ushort4*)(ma.qf + (size_t)row * 256 + col0) = st;
      }
    }
  } else {
    // swapped layout: row = r0 + mr*16 + (l&15); cols = c0 + nr*16 + (l>>4)*4 + i
    const int rowl = l & 15, colq = (l >> 4) * 4;
#pragma unroll
    for (int mr = 0; mr < 4; ++mr) {
      int row = r0 + mr * 16 + rowl;
#pragma unroll
      for (int nr = 0; nr < 4; ++nr) {
        int col0 = c0 + nr * 16 + colq;
        if constexpr (MODE == GLOW) {
          if (col0 < 192) {
            float dl = ma.delayed[row];
            float4 wd = *(const float4*)(ma.wl_d + col0);
            float4 bp = *(const float4*)(ma.bl_p + col0);
            ushort4 st = {f2bf(acc[mr][nr][0] + dl * wd.x + bp.x),
                          f2bf(acc[mr][nr][1] + dl * wd.y + bp.y),
                          f2bf(acc[mr][nr][2] + dl * wd.z + bp.z),
                          f2bf(acc[mr][nr][3] + dl * wd.w + bp.w)};
            *(ushort4*)(ma.low + (size_t)row * 192 + col0) = st;
          }
        } else {  // GGEO
          u16* dst = ma.geopart + (size_t)bz * 4194304;
          ushort4 st = {f2bf(acc[mr][nr][0]), f2bf(acc[mr][nr][1]),
                        f2bf(acc[mr][nr][2]), f2bf(acc[mr][nr][3])};
          *(ushort4*)(dst + (size_t)row * 2048 + col0) = st;
        }
      }
    }
  }
}

// ---------------- gkv: per (head, 128-row chunk) compute k_h/v_h tile, then kv+ksum in-LDS ----------------
__global__ __launch_bounds__(256) void gkv_k(const u16* __restrict__ low,
                                             const u16* __restrict__ wqhTkv,
                                             const float* __restrict__ bqh,
                                             float* __restrict__ kvpart,
                                             float* __restrict__ kspart) {
  __shared__ __align__(16) u16 SH[17152];      // 34304 B
  u16* Al = SH;
  u16* Bl = SH + 128 * 64;
  u16* T  = SH;                                // [64][136] bf16, after barrier
  float* kvs = (float*)((char*)SH + 17408);    // [4][32][32]
  float* kss = (float*)((char*)SH + 17408 + 16384);  // [4][32]

  const int t = threadIdx.x;
  const int l = t & 63, w = t >> 6;

  int lin = blockIdx.x + 8 * blockIdx.y;
  int xcd = lin & 7, idx = lin >> 3;
  const int h = idx & 7;
  const int rt = xcd * 64 + (idx >> 3);
  const int b = rt >> 4, p = rt & 15;

  f4v acc[2][4] = {};

  for (int k0 = 0; k0 < 192; k0 += 64) {
    __syncthreads();
#pragma unroll
    for (int s = 0; s < 4; ++s) {
      int c = s * 256 + t;
      int r = c >> 3, cc = c & 7;
      int g = ((cc & 3) ^ ((r >> 1) & 3)) | ((cc & 4) ^ ((r & 1) << 2));
      gload16(low + (size_t)(rt * 128 + r) * 192 + k0 + g * 8,
              (char*)Al + (s * 4 + w) * 1024);
    }
#pragma unroll
    for (int s = 0; s < 2; ++s) {
      int c = s * 256 + t;
      int r = c >> 3, cc = c & 7;
      int g = ((cc & 3) ^ ((r >> 1) & 3)) | ((cc & 4) ^ ((r & 1) << 2));
      int wqrow = (r < 32) ? (h * 32 + r) : (256 + h * 32 + (r - 32));
      gload16(wqhTkv + (size_t)wqrow * 192 + k0 + g * 8,
              (char*)Bl + (s * 4 + w) * 1024);
    }
    __syncthreads();

#pragma unroll
    for (int kk = 0; kk < 64; kk += 32) {
      s8v fa[2], fb[4];
#pragma unroll
      for (int mr = 0; mr < 2; ++mr) {
        int ra = w * 32 + mr * 16 + (l & 15);
        int ch = ((l >> 4) ^ ((ra >> 1) & 3)) | ((kk >> 3) ^ ((ra & 1) << 2));
        fa[mr] = *(const s8v*)(Al + ra * 64 + ch * 8);
      }
#pragma unroll
      for (int nr = 0; nr < 4; ++nr) {
        int rb = nr * 16 + (l & 15);
        int cb = ((l >> 4) ^ ((rb >> 1) & 3)) | ((kk >> 3) ^ ((rb & 1) << 2));
        fb[nr] = *(const s8v*)(Bl + rb * 64 + cb * 8);
      }
#pragma unroll
      for (int mr = 0; mr < 2; ++mr)
#pragma unroll
        for (int nr = 0; nr < 4; ++nr)
          acc[mr][nr] = __builtin_amdgcn_mfma_f32_16x16x32_bf16(fa[mr], fb[nr], acc[mr][nr], 0, 0, 0);
    }
  }

  const int lr = (l >> 4) * 4, lc = l & 15;
  __syncthreads();
#pragma unroll
  for (int nr = 0; nr < 4; ++nr) {
    int cl = nr * 16 + lc;
    float bias = (cl < 32) ? bqh[256 + h * 32 + cl] : bqh[512 + h * 32 + (cl - 32)];
#pragma unroll
    for (int mr = 0; mr < 2; ++mr) {
      int n_l = w * 32 + mr * 16 + lr;
      float v0 = acc[mr][nr][0] + bias;
      float v1 = acc[mr][nr][1] + bias;
      float v2 = acc[mr][nr][2] + bias;
      float v3 = acc[mr][nr][3] + bias;
      if (cl < 32) {
        v0 = (v0 > 0.f) ? (v0 + 1.f) : __expf(v0);
        v1 = (v1 > 0.f) ? (v1 + 1.f) : __expf(v1);
        v2 = (v2 > 0.f) ? (v2 + 1.f) : __expf(v2);
        v3 = (v3 > 0.f) ? (v3 + 1.f) : __expf(v3);
      }
      ushort4 st = {f2bf(v0), f2bf(v1), f2bf(v2), f2bf(v3)};
      *(ushort4*)&T[cl * 136 + n_l] = st;
    }
  }
  __syncthreads();

  f4v acc2[2][2] = {};
  float ks[2] = {0.f, 0.f};
  {
    int koff = w * 32 + (l >> 4) * 8;
    s8v fa2[2], fb2[2];
#pragma unroll
    for (int mr = 0; mr < 2; ++mr)
      fa2[mr] = *(const s8v*)&T[(mr * 16 + (l & 15)) * 136 + koff];
#pragma unroll
    for (int nr = 0; nr < 2; ++nr)
      fb2[nr] = *(const s8v*)&T[(32 + nr * 16 + (l & 15)) * 136 + koff];
#pragma unroll
    for (int mr = 0; mr < 2; ++mr) {
      float sacc = 0.f;
#pragma unroll
      for (int j = 0; j < 8; ++j) sacc += bf2f((u16)fa2[mr][j]);
      ks[mr] = sacc;
    }
#pragma unroll
    for (int mr = 0; mr < 2; ++mr)
#pragma unroll
      for (int nr = 0; nr < 2; ++nr)
        acc2[mr][nr] = __builtin_amdgcn_mfma_f32_16x16x32_bf16(fa2[mr], fb2[nr], acc2[mr][nr], 0, 0, 0);
  }
  ks[0] += __shfl_xor(ks[0], 16); ks[0] += __shfl_xor(ks[0], 32);
  ks[1] += __shfl_xor(ks[1], 16); ks[1] += __shfl_xor(ks[1], 32);

#pragma unroll
  for (int mr = 0; mr < 2; ++mr)
#pragma unroll
    for (int nr = 0; nr < 2; ++nr)
#pragma unroll
      for (int i = 0; i < 4; ++i)
        kvs[(size_t)w * 1024 + (mr * 16 + (l >> 4) * 4 + i) * 32 + nr * 16 + (l & 15)] =
            acc2[mr][nr][i];
  if (l < 16) { kss[w * 32 + l] = ks[0]; kss[w * 32 + 16 + l] = ks[1]; }
  __syncthreads();

  float* kvp = kvpart + ((size_t)(p * 256 + b * 8 + h)) * 1024;
#pragma unroll
  for (int q = 0; q < 4; ++q) {
    int idx2 = q * 256 + t;
    kvp[idx2] = kvs[idx2] + kvs[1024 + idx2] + kvs[2048 + idx2] + kvs[3072 + idx2];
  }
  if (t < 32)
    kspart[((size_t)(p * 256 + b * 8 + h)) * 32 + t] =
        kss[t] + kss[32 + t] + kss[64 + t] + kss[96 + t];
}

// ---------------- GFIN: 64x256 tile, BK=64, peeled geo iteration, fused residual+LN ----------------
__global__ __launch_bounds__(256) void gfin_k(const u16* __restrict__ qs,
                                              const u16* __restrict__ geopart,
                                              const u16* __restrict__ B2t,
                                              const float* __restrict__ cvec,
                                              const float* __restrict__ feats,
                                              const float* __restrict__ gamma,
                                              const float* __restrict__ beta,
                                              float* __restrict__ y) {
  __shared__ __align__(16) u16 Al[64 * 64];     // 8KB (doubles as LN buffers post-loop)
  __shared__ __align__(16) u16 Bl[256 * 64];    // 32KB
  float* LN1 = (float*)Al;                      // [4][64] aliased
  float* LN2 = LN1 + 256;

  const int t = threadIdx.x;
  const int l = t & 63, w = t >> 6;             // w = col quadrant (0..3)
  const int rt = blockIdx.x;
  const int b = rt >> 5;

  f4v acc[4][4] = {};

  // ---- main loop: k0 = 0..192, branch-free pure-gload16 staging ----
  for (int k0 = 0; k0 < 256; k0 += 64) {
    __syncthreads();
#pragma unroll
    for (int s = 0; s < 2; ++s) {
      int c = s * 256 + t;               // 0..511
      int r = c >> 3, cc = c & 7;
      int g = ((cc & 3) ^ ((r >> 1) & 3)) | ((cc & 4) ^ ((r & 1) << 2));
      gload16(qs + (size_t)(rt * 64 + r) * 256 + k0 + g * 8,
              (char*)Al + (s * 4 + w) * 1024);
    }
#pragma unroll
    for (int s = 0; s < 8; ++s) {
      int c = s * 256 + t;               // 0..2047
      int r = c >> 3, cc = c & 7;
      int g = ((cc & 3) ^ ((r >> 1) & 3)) | ((cc & 4) ^ ((r & 1) << 2));
      gload16(B2t + ((size_t)b * 256 + r) * 320 + k0 + g * 8,
              (char*)Bl + (s * 4 + w) * 1024);
    }
    __syncthreads();

#pragma unroll
    for (int kk = 0; kk < 64; kk += 32) {
      s8v fa[4], fb[4];
#pragma unroll
      for (int mr = 0; mr < 4; ++mr) {
        int ra = mr * 16 + (l & 15);
        int ch = ((l >> 4) ^ ((ra >> 1) & 3)) | ((kk >> 3) ^ ((ra & 1) << 2));
        fa[mr] = *(const s8v*)(Al + ra * 64 + ch * 8);
      }
#pragma unroll
      for (int nr = 0; nr < 4; ++nr) {
        int rb = w * 64 + nr * 16 + (l & 15);
        int cb = ((l >> 4) ^ ((rb >> 1) & 3)) | ((kk >> 3) ^ ((rb & 1) << 2));
        fb[nr] = *(const s8v*)(Bl + rb * 64 + cb * 8);
      }
#pragma unroll
      for (int mr = 0; mr < 4; ++mr)
#pragma unroll
        for (int nr = 0; nr < 4; ++nr)
          acc[mr][nr] = __builtin_amdgcn_mfma_f32_16x16x32_bf16(fb[nr], fa[mr], acc[mr][nr], 0, 0, 0);
    }
  }

  // ---- peeled geo iteration (k0 = 256) ----
  {
    __syncthreads();
#pragma unroll
    for (int s = 0; s < 2; ++s) {
      int c = s * 256 + t;
      int r = c >> 3, cc = c & 7;
      int g = ((cc & 3) ^ ((r >> 1) & 3)) | ((cc & 4) ^ ((r & 1) << 2));
      int row = rt * 64 + r;
      int n = row & 2047;
      const u16* gp = geopart + (size_t)n * 2048 + b * 64 + g * 8;
      s8v p0 = *(const s8v*)(gp);
      s8v p1 = *(const s8v*)(gp + 4194304);
      s8v p2 = *(const s8v*)(gp + 8388608);
      s8v p3 = *(const s8v*)(gp + 12582912);
      float vv[8];
#pragma unroll
      for (int j = 0; j < 8; ++j)
        vv[j] = bf2f((u16)p0[j]) + bf2f((u16)p1[j]) + bf2f((u16)p2[j]) + bf2f((u16)p3[j]);
      uint4 qq = {pk2(vv[0], vv[1]), pk2(vv[2], vv[3]), pk2(vv[4], vv[5]), pk2(vv[6], vv[7])};
      *(uint4*)&Al[c * 8] = qq;
    }
#pragma unroll
    for (int s = 0; s < 8; ++s) {
      int c = s * 256 + t;
      int r = c >> 3, cc = c & 7;
      int g = ((cc & 3) ^ ((r >> 1) & 3)) | ((cc & 4) ^ ((r & 1) << 2));
      gload16(B2t + ((size_t)b * 256 + r) * 320 + 256 + g * 8,
              (char*)Bl + (s * 4 + w) * 1024);
    }
    __syncthreads();

#pragma unroll
    for (int kk = 0; kk < 64; kk += 32) {
      s8v fa[4], fb[4];
#pragma unroll
      for (int mr = 0; mr < 4; ++mr) {
        int ra = mr * 16 + (l & 15);
        int ch = ((l >> 4) ^ ((ra >> 1) & 3)) | ((kk >> 3) ^ ((ra & 1) << 2));
        fa[mr] = *(const s8v*)(Al + ra * 64 + ch * 8);
      }
#pragma unroll
      for (int nr = 0; nr < 4; ++nr) {
        int rb = w * 64 + nr * 16 + (l & 15);
        int cb = ((l >> 4) ^ ((rb >> 1) & 3)) | ((kk >> 3) ^ ((rb & 1) << 2));
        fb[nr] = *(const s8v*)(Bl + rb * 64 + cb * 8);
      }
#pragma unroll
      for (int mr = 0; mr < 4; ++mr)
#pragma unroll
        for (int nr = 0; nr < 4; ++nr)
          acc[mr][nr] = __builtin_amdgcn_mfma_f32_16x16x32_bf16(fb[nr], fa[mr], acc[mr][nr], 0, 0, 0);
    }
  }

  // ---- epilogue: y = out + feats, LayerNorm over 256 cols ----
  const int rowl = l & 15, colq = (l >> 4) * 4;
  float s1v[4] = {0.f, 0.f, 0.f, 0.f}, s2v[4] = {0.f, 0.f, 0.f, 0.f};
#pragma unroll
  for (int mr = 0; mr < 4; ++mr) {
    int row = rt * 64 + mr * 16 + rowl;
#pragma unroll
    for (int nr = 0; nr < 4; ++nr) {
      int col0 = w * 64 + nr * 16 + colq;
      float4 cv = *(const float4*)(cvec + col0);
      float4 ft = *(const float4*)(feats + (size_t)row * 256 + col0);
      f4v vv = acc[mr][nr];
      vv[0] += cv.x + ft.x; vv[1] += cv.y + ft.y;
      vv[2] += cv.z + ft.z; vv[3] += cv.w + ft.w;
      acc[mr][nr] = vv;
      s1v[mr] += vv[0] + vv[1] + vv[2] + vv[3];
      s2v[mr] += vv[0] * vv[0] + vv[1] * vv[1] + vv[2] * vv[2] + vv[3] * vv[3];
    }
  }
#pragma unroll
  for (int mr = 0; mr < 4; ++mr) {
    s1v[mr] += __shfl_xor(s1v[mr], 16); s2v[mr] += __shfl_xor(s2v[mr], 16);
    s1v[mr] += __shfl_xor(s1v[mr], 32); s2v[mr] += __shfl_xor(s2v[mr], 32);
  }
  __syncthreads();                 // all Al fragment reads complete before aliasing
  if (l < 16) {
#pragma unroll
    for (int mr = 0; mr < 4; ++mr) {
      LN1[w * 64 + mr * 16 + l] = s1v[mr];
      LN2[w * 64 + mr * 16 + l] = s2v[mr];
    }
  }
  __syncthreads();
#pragma unroll
  for (int mr = 0; mr < 4; ++mr) {
    int rl = mr * 16 + rowl;
    int row = rt * 64 + rl;
    float s1 = LN1[rl] + LN1[64 + rl] + LN1[128 + rl] + LN1[192 + rl];
    float s2 = LN2[rl] + LN2[64 + rl] + LN2[128 + rl] + LN2[192 + rl];
    float mu = s1 * (1.f / 256.f);
    float var = s2 * (1.f / 256.f) - mu * mu;
    float rstd = rsqrtf(fmaxf(var, 0.f) + 1e-5f);
#pragma unroll
    for (int nr = 0; nr < 4; ++nr) {
      int col0 = w * 64 + nr * 16 + colq;
      float4 g4 = *(const float4*)(gamma + col0);
      float4 b4 = *(const float4*)(beta + col0);
      f4v vv = acc[mr][nr];
      float4 o;
      o.x = (vv[0] - mu) * rstd * g4.x + b4.x;
      o.y = (vv[1] - mu) * rstd * g4.y + b4.y;
      o.z = (vv[2] - mu) * rstd * g4.z + b4.z;
      o.w = (vv[3] - mu) * rstd * g4.w + b4.w;
      *(float4*)(y + (size_t)row * 256 + col0) = o;
    }
  }
}

// ---------------- M[b,h] = (1-gb) * kv[b,h] @ Wl_h (fp32 kvpart x16) ----------------
__global__ __launch_bounds__(64) void mmat_k(const float* __restrict__ kvpart,
                                             const float* __restrict__ wol,
                                             const float* __restrict__ geow,
                                             float* __restrict__ Mm) {
  const int bh = blockIdx.x;
  const int h = bh & 7, b = bh >> 3;
  const int c = threadIdx.x;
  __shared__ float kvs[32][32];
  for (int i = c; i < 1024; i += 64) {
    float s = 0.f;
#pragma unroll
    for (int p = 0; p < 16; ++p) s += kvpart[(size_t)(p * 256 + bh) * 1024 + i];
    kvs[i >> 5][i & 31] = s;
  }
  __syncthreads();
  float one_m = 1.f - 1.f / (1.f + __expf(-geow[0]));
  float acc[32];
#pragma unroll
  for (int d = 0; d < 32; ++d) acc[d] = 0.f;
  for (int e = 0; e < 32; ++e) {
    float w = wol[(size_t)(h * 32 + e) * 64 + c];
#pragma unroll
    for (int d = 0; d < 32; ++d) acc[d] = fmaf(kvs[d][e], w, acc[d]);
  }
  float* mp = Mm + (size_t)b * 16384 + (size_t)h * 32 * 64 + c;
#pragma unroll
  for (int d = 0; d < 32; ++d) mp[d * 64] = one_m * acc[d];
}

// ---------------- B2t[b][c][320] = [ (Mm[b]@Woh)^T ; gb*Woh^T ] ; cvec ----------------
__global__ __launch_bounds__(256) void bprep_k(const float* __restrict__ Mm,
                                               const float* __restrict__ woh,
                                               const float* __restrict__ bol,
                                               const float* __restrict__ boh,
                                               const float* __restrict__ geow,
                                               u16* __restrict__ B2t,
                                               float* __restrict__ cvec) {
  const int kt = blockIdx.x, b = blockIdx.y;   // kt<4 (64 k each)
  const int c = threadIdx.x;                   // 0..255
  __shared__ float Ms[64][64];
#pragma unroll
  for (int i = 0; i < 16; ++i) {
    int flat = c + i * 256;
    int kk = flat >> 6, e = flat & 63;
    Ms[kk][e] = Mm[(size_t)b * 16384 + (size_t)(kt * 64 + kk) * 64 + e];
  }
  __syncthreads();
  float wcol[64];
#pragma unroll
  for (int e = 0; e < 64; ++e) wcol[e] = woh[(size_t)e * 256 + c];
  u16* dst = B2t + ((size_t)b * 256 + c) * 320;
  for (int kk = 0; kk < 64; ++kk) {
    float s = 0.f;
#pragma unroll
    for (int e = 0; e < 64; ++e) s = fmaf(Ms[kk][e], wcol[e], s);
    dst[kt * 64 + kk] = f2bf(s);
  }
  if (kt == 0) {
    float gb = 1.f / (1.f + __expf(-geow[0]));
#pragma unroll
    for (int d = 0; d < 64; ++d) dst[256 + d] = f2bf(gb * wcol[d]);
    if (b == 0) {
      float s = boh[c];
#pragma unroll
      for (int d = 0; d < 64; ++d) s = fmaf(bol[d], wcol[d], s);
      cvec[c] = s;
    }
  }
}

// ---------------- host ----------------
extern "C" void kernel_launch(void* const* d_in, const int* in_sizes, int n_in,
                              void* d_out, int out_size, void* d_ws, size_t ws_size,
                              hipStream_t stream) {
  const float* x     = (const float*)d_in[0];
  const float* feats = (const float*)d_in[1];
  const float* dlog  = (const float*)d_in[2];
  const float* w_dp  = (const float*)d_in[3];
  const float* b_dp  = (const float*)d_in[4];
  const float* wql   = (const float*)d_in[5];
  const float* bql   = (const float*)d_in[6];
  const float* wqh   = (const float*)d_in[7];
  const float* bqh   = (const float*)d_in[8];
  const float* wol   = (const float*)d_in[9];
  const float* bol   = (const float*)d_in[10];
  const float* woh   = (const float*)d_in[11];
  const float* boh   = (const float*)d_in[12];
  const float* adj   = (const float*)d_in[13];
  const float* geow  = (const float*)d_in[14];
  const float* gamma = (const float*)d_in[15];
  const float* beta  = (const float*)d_in[16];

  char* ws = (char*)d_ws;
  // high-water 136,273,920 B (proven)
  constexpr size_t OFF_WLD   = 1024;
  constexpr size_t OFF_BLP   = 2048;
  constexpr size_t OFF_CVEC  = 4096;
  constexpr size_t OFF_CVL   = 5120;
  constexpr size_t OFF_DEL   = 8192;        // 256KB -> 270336
  constexpr size_t OFF_WQLT  = 270336;      // -> 401408
  constexpr size_t OFF_WQHT  = 401408;      // -> 696320
  constexpr size_t OFF_WVLT  = 696320;      // -> 745472
  constexpr size_t OFF_MM    = 2973696;     // 2MB -> 5070848
  constexpr size_t OFF_B2T   = 5070848;     // 5MB -> 10313728 (< OFF_LOW)
  constexpr size_t OFF_LOW   = 10444800;    // 24MB [GLOW..GVP]
  constexpr size_t OFF_QF    = 35610624;    // 32MB qs [GQ..gfin]
  constexpr size_t OFF_KF    = 69165056;    // 32MB region
  constexpr size_t OFF_VPT   = OFF_KF;                 // 8MB [GVP..GGEO]
  constexpr size_t OFF_ADJB  = OFF_KF + 8388608;       // 8MB [cvtadj..GGEO]
  constexpr size_t OFF_V     = 102719488;   // 32MB region
  constexpr size_t OFF_KVP   = OFF_V;                  // 16MB fp32 [gkv..mmat]
  constexpr size_t OFF_KSP   = OFF_V + 16777216;       // 512KB [gkv..GQ]
  constexpr size_t OFF_GPART = OFF_V;                  // 4x8MB [GGEO..gfin] (after mmat/GQ)

  float* wl_d    = (float*)(ws + OFF_WLD);
  float* bl_p    = (float*)(ws + OFF_BLP);
  float* cvec    = (float*)(ws + OFF_CVEC);
  float* cvl     = (float*)(ws + OFF_CVL);
  float* delayed = (float*)(ws + OFF_DEL);
  float* kspart  = (float*)(ws + OFF_KSP);
  float* Mm      = (float*)(ws + OFF_MM);
  float* kvpart  = (float*)(ws + OFF_KVP);
  u16* wqlT = (u16*)(ws + OFF_WQLT);
  u16* wqhT = (u16*)(ws + OFF_WQHT);
  u16* wvlT = (u16*)(ws + OFF_WVLT);
  u16* B2t  = (u16*)(ws + OFF_B2T);
  u16* adjb = (u16*)(ws + OFF_ADJB);

  MArgs ma{};
  ma.delayed = delayed; ma.wl_d = wl_d; ma.bl_p = bl_p; ma.bqh = bqh; ma.cvl = cvl;
  ma.adjb = adjb;
  ma.kspart = kspart;
  ma.low = (u16*)(ws + OFF_LOW);
  ma.qf  = (u16*)(ws + OFF_QF);     // pre-scaled qs
  ma.vpt = (u16*)(ws + OFF_VPT);
  ma.geopart = (u16*)(ws + OFF_GPART);

  prep_all_k<<<1409, 256, 0, stream>>>(x, dlog, w_dp, b_dp, wql, bql, wqh, wol, bqh,
                                       wl_d, bl_p, delayed, wqlT, wqhT, wvlT, cvl);

  MArgs m0 = ma; m0.Af32 = feats; m0.Bt = wqlT;
  mgemm_k<GLOW><<<dim3(2, 512), 256, 0, stream>>>(m0);        // low (bf16)

  gkv_k<<<dim3(8, 512), 256, 0, stream>>>(ma.low, wqhT + (size_t)256 * 192, bqh,
                                          kvpart, kspart);    // kv + ksum partials

  MArgs m1 = ma; m1.A = ma.low; m1.Bt = wqhT;
  mgemm_k<GQ><<<dim3(2, 512), 256, 0, stream>>>(m1);          // qs = elu(q)/den (pre-scaled)

  cvtadj_k<<<2048, 256, 0, stream>>>(adj, adjb);              // adj -> bf16
  mmat_k<<<256, 64, 0, stream>>>(kvpart, wol, geow, Mm);
  bprep_k<<<dim3(4, 32), 256, 0, stream>>>(Mm, woh, bol, boh, geow, B2t, cvec);

  MArgs m2 = ma; m2.A = ma.low; m2.Bt = wvlT;
  mgemm_k<GVP><<<dim3(1, 512), 256, 0, stream>>>(m2);         // vpt = (low@Wvl+cvl)^T bf16

  MArgs m3 = ma; m3.Bt = ma.vpt;
  mgemm_k<GGEO><<<dim3(16, 16, 4), 256, 0, stream>>>(m3);     // split-K=4 partials

  gfin_k<<<1024, 256, 0, stream>>>(ma.qf, ma.geopart, B2t, cvec,
                                   feats, gamma, beta, (float*)d_out);
  (void)in_sizes; (void)n_in; (void)out_size; (void)ws_size;
}

// Round 20
// 236.966 us; speedup vs baseline: 1.0267x; 1.0267x over previous
//
#include <hip/hip_runtime.h>
#include <hip/hip_bf16.h>
#include <stdint.h>

typedef unsigned short u16;
typedef float f4v __attribute__((ext_vector_type(4)));
typedef short s8v __attribute__((ext_vector_type(8)));

// B=32, T=64, N=2048, HID=256, HEADS=8, DH=32, BOT=64, MAX_LAG=7 ; rows = 65536

__device__ __forceinline__ float bf2f(u16 u) {
  union { float f; uint32_t i; } x; x.i = ((uint32_t)u) << 16; return x.f;
}
__device__ __forceinline__ u16 f2bf(float f) {
  uint32_t u = __float_as_uint(f);
  u = (u + 0x7FFFu + ((u >> 16) & 1u)) >> 16;
  return (u16)u;
}
__device__ __forceinline__ uint32_t pk2(float a, float b) {
  return (uint32_t)f2bf(a) | ((uint32_t)f2bf(b) << 16);
}
__device__ __forceinline__ void gload16(const void* g, void* l) {
  __builtin_amdgcn_global_load_lds((const __attribute__((address_space(1))) void*)g,
                                   (__attribute__((address_space(3))) void*)l, 16, 0, 0);
}

// ---------------- prep_all: delayed + weight transposes + folded delay weights ----------------
__global__ __launch_bounds__(256) void prep_all_k(
    const float* __restrict__ x, const float* __restrict__ dlog,
    const float* __restrict__ w_dp, const float* __restrict__ b_dp,
    const float* __restrict__ wql, const float* __restrict__ bql,
    const float* __restrict__ wqh, const float* __restrict__ wol,
    const float* __restrict__ bqh,
    float* __restrict__ wl_d, float* __restrict__ bl_p, float* __restrict__ delayed,
    u16* __restrict__ wqlT, u16* __restrict__ wqhT, u16* __restrict__ wvlT,
    float* __restrict__ cvl) {
  const int bid = blockIdx.x, t = threadIdx.x;
  if (bid < 256) {
    float mx = dlog[0];
#pragma unroll
    for (int i = 1; i < 8; ++i) mx = fmaxf(mx, dlog[i]);
    float w8[8], ssum = 0.f;
#pragma unroll
    for (int i = 0; i < 8; ++i) { w8[i] = __expf(dlog[i] - mx); ssum += w8[i]; }
    float inv = 1.f / ssum;
    int r = bid * 256 + t;
    int b = r >> 11, n = r & 2047;
    const float* xb = x + (size_t)b * 64 * 2048;
    float acc = 0.f;
#pragma unroll
    for (int tau = 0; tau < 8; ++tau) acc += w8[tau] * inv * xb[(size_t)(63 - tau) * 2048 + n];
    delayed[r] = acc;
  } else if (bid < 512) {
    int n = bid - 256;
    wqlT[(size_t)n * 256 + t] = f2bf(n < 192 ? wql[(size_t)t * 192 + n] : 0.f);
  } else if (bid < 1280) {
    int n = bid - 512;
    if (t < 192) wqhT[(size_t)n * 192 + t] = f2bf(wqh[(size_t)t * 768 + n]);
  } else if (bid < 1408) {
    int d = bid - 1280;   // 0..127 (pad to 128)
    __shared__ float wolc[256];
    if (d < 64) wolc[t] = wol[(size_t)t * 64 + d];
    __syncthreads();
    if (t < 192) {
      float s = 0.f;
      if (d < 64) {
        const float* wr = wqh + (size_t)t * 768 + 512;
        for (int c = 0; c < 256; ++c) s = fmaf(wr[c], wolc[c], s);
      }
      wvlT[(size_t)d * 192 + t] = f2bf(s);
    }
    if (t == 0 && d < 64) {
      float s = 0.f;
      for (int c = 0; c < 256; ++c) s = fmaf(bqh[512 + c], wolc[c], s);
      cvl[d] = s;
    }
  } else {
    if (t < 192) {
      float s1 = 0.f, s2 = 0.f;
      for (int k = 0; k < 256; ++k) {
        float w = wql[k * 192 + t];
        s1 += w_dp[k] * w;
        s2 += b_dp[k] * w;
      }
      wl_d[t] = 0.1f * s1;
      bl_p[t] = bql[t] + 0.1f * s2;
    }
  }
}

// ---------------- adj fp32 -> bf16 ----------------
__global__ __launch_bounds__(256) void cvtadj_k(const float* __restrict__ in,
                                                u16* __restrict__ out) {
  size_t i = ((size_t)blockIdx.x * 256 + threadIdx.x) * 8;
  float4 a = *(const float4*)(in + i);
  float4 b = *(const float4*)(in + i + 4);
  uint4 q = {pk2(a.x, a.y), pk2(a.z, a.w), pk2(b.x, b.y), pk2(b.z, b.w)};
  *(uint4*)(out + i) = q;
}

// ---------------- bf16 MFMA GEMM template (128x128 tile, BK=64, 4 waves) ----------------
struct MArgs {
  const u16* A;        // GQ/GVP: low
  const float* Af32;   // GLOW: features (fp32, reg-staged)
  const u16* adjb;     // GGEO: adj bf16 (gload16)
  const u16* Bt;
  const float* delayed; const float* wl_d; const float* bl_p;   // GLOW
  const float* bqh;                                             // GQ
  const float* cvl;                                             // GVP
  const float* kspart; float* rden;                             // GQ (fused rden)
  u16* low; u16* qf; u16* vpt;
  u16* geopart;        // GGEO split-K partials
};

enum { GLOW = 0, GQ = 1, GGEO = 2, GVP = 3 };

template <int MODE>
__global__ __launch_bounds__(256) void mgemm_k(MArgs ma) {
  constexpr int KLOOP = (MODE == GLOW) ? 256 : (MODE == GGEO) ? 512 : 192;
  constexpr int LDA = (MODE == GLOW) ? 256 : (MODE == GGEO) ? 2048 : 192;
  constexpr int LDB = (MODE == GLOW) ? 256 : (MODE == GGEO) ? 2048 : 192;
  constexpr bool SWAPPED = (MODE != GVP);

  __shared__ __align__(16) u16 SH[128 * 128];
  u16* Al = SH;
  u16* Bl = SH + 128 * 64;

  const int t = threadIdx.x;
  const int l = t & 63, w = t >> 6;
  const int wm = w >> 1, wn = w & 1;

  // XCD-aware (ct,rt): colocate blocks sharing an A panel on one XCD
  int ct, rt, bz = 0;
  if constexpr (MODE == GGEO) {
    int lin = blockIdx.x + 16 * blockIdx.y + 256 * blockIdx.z;
    int xcd = lin & 7, idx = lin >> 3;
    ct = idx & 15;
    int pid = xcd * 8 + (idx >> 4);   // 0..63
    rt = pid & 15;
    bz = pid >> 4;                    // 0..3
  } else {
    constexpr int NCT = (MODE == GVP) ? 1 : 2;
    int lin = blockIdx.x + NCT * blockIdx.y;
    int xcd = lin & 7, idx = lin >> 3;
    ct = idx % NCT; rt = xcd * 64 + idx / NCT;
  }
  const int kbase = (MODE == GGEO) ? bz * 512 : 0;

  f4v acc[4][4] = {};

  for (int k0 = 0; k0 < KLOOP; k0 += 64) {
    __syncthreads();
#pragma unroll
    for (int s = 0; s < 4; ++s) {
      int c = s * 256 + t;                 // 0..1023
      int r = c >> 3, cc = c & 7;
      int g = ((cc & 3) ^ ((r >> 1) & 3)) | ((cc & 4) ^ ((r & 1) << 2));
      int row = rt * 128 + r;
      int kg = kbase + k0 + g * 8;
      if constexpr (MODE == GLOW) {
        const float* src = ma.Af32 + (size_t)row * LDA + kg;
        float4 x0 = *(const float4*)src;
        float4 x1 = *(const float4*)(src + 4);
        uint4 qq = {pk2(x0.x, x0.y), pk2(x0.z, x0.w), pk2(x1.x, x1.y), pk2(x1.z, x1.w)};
        *(uint4*)&Al[c * 8] = qq;
      } else if constexpr (MODE == GGEO) {
        gload16(ma.adjb + (size_t)row * 2048 + kg, (char*)Al + (s * 4 + w) * 1024);
      } else {
        gload16(ma.A + (size_t)row * LDA + kg, (char*)Al + (s * 4 + w) * 1024);
      }
      gload16(ma.Bt + (size_t)(ct * 128 + r) * LDB + kg,
              (char*)Bl + (s * 4 + w) * 1024);
    }
    __syncthreads();

#pragma unroll
    for (int kk = 0; kk < 64; kk += 32) {
      s8v fa[4], fb[4];
#pragma unroll
      for (int mr = 0; mr < 4; ++mr) {
        int ra = wm * 64 + mr * 16 + (l & 15);
        int ch = ((l >> 4) ^ ((ra >> 1) & 3)) | ((kk >> 3) ^ ((ra & 1) << 2));
        fa[mr] = *(const s8v*)(Al + ra * 64 + ch * 8);
      }
#pragma unroll
      for (int nr = 0; nr < 4; ++nr) {
        int rb = wn * 64 + nr * 16 + (l & 15);
        int cb = ((l >> 4) ^ ((rb >> 1) & 3)) | ((kk >> 3) ^ ((rb & 1) << 2));
        fb[nr] = *(const s8v*)(Bl + rb * 64 + cb * 8);
      }
      if constexpr (SWAPPED) {
#pragma unroll
        for (int mr = 0; mr < 4; ++mr)
#pragma unroll
          for (int nr = 0; nr < 4; ++nr)
            acc[mr][nr] = __builtin_amdgcn_mfma_f32_16x16x32_bf16(fb[nr], fa[mr], acc[mr][nr], 0, 0, 0);
      } else {
#pragma unroll
        for (int mr = 0; mr < 4; ++mr)
#pragma unroll
          for (int nr = 0; nr < 4; ++nr)
            acc[mr][nr] = __builtin_amdgcn_mfma_f32_16x16x32_bf16(fa[mr], fb[nr], acc[mr][nr], 0, 0, 0);
      }
    }
  }

  const int r0 = rt * 128 + wm * 64, c0 = ct * 128 + wn * 64;

  if constexpr (MODE == GVP) {
    const int lr = (l >> 4) * 4, lc = l & 15;
#pragma unroll
    for (int mr = 0; mr < 4; ++mr)
#pragma unroll
      for (int nr = 0; nr < 4; ++nr) {
        if (wn == 0) {
          int d = nr * 16 + lc;
          float cadd = ma.cvl[d];
          int n0 = (r0 + mr * 16 + lr) & 2047;
          int b = rt >> 4;
          ushort4 st = {f2bf(acc[mr][nr][0] + cadd), f2bf(acc[mr][nr][1] + cadd),
                        f2bf(acc[mr][nr][2] + cadd), f2bf(acc[mr][nr][3] + cadd)};
          *(ushort4*)(ma.vpt + ((size_t)(b * 64 + d)) * 2048 + n0) = st;
        }
      }
  } else if constexpr (MODE == GQ) {
    // ---- ksumf into aliased LDS (staging done) ----
    __syncthreads();
    float* ksumf = (float*)SH;
    {
      int bb = rt >> 4;
      float s = 0.f;
#pragma unroll
      for (int p = 0; p < 16; ++p)
        s += ma.kspart[(size_t)(p * 256 + bb * 8 + (t >> 5)) * 32 + (t & 31)];
      ksumf[t] = s + 1e-8f;
    }
    __syncthreads();
    const int rowl = l & 15, colq = (l >> 4) * 4;
    float dp[4][2] = {};
#pragma unroll
    for (int mr = 0; mr < 4; ++mr) {
      int row = r0 + mr * 16 + rowl;
#pragma unroll
      for (int nr = 0; nr < 4; ++nr) {
        int col0 = c0 + nr * 16 + colq;
        float4 bias = *(const float4*)(ma.bqh + col0);
        float v0 = acc[mr][nr][0] + bias.x;
        float v1 = acc[mr][nr][1] + bias.y;
        float v2 = acc[mr][nr][2] + bias.z;
        float v3 = acc[mr][nr][3] + bias.w;
        v0 = (v0 > 0.f) ? (v0 + 1.f) : __expf(v0);
        v1 = (v1 > 0.f) ? (v1 + 1.f) : __expf(v1);
        v2 = (v2 > 0.f) ? (v2 + 1.f) : __expf(v2);
        v3 = (v3 > 0.f) ? (v3 + 1.f) : __expf(v3);
        ushort4 st = {f2bf(v0), f2bf(v1), f2bf(v2), f2bf(v3)};
        *(ushort4*)(ma.qf + (size_t)row * 256 + col0) = st;
        float r0f = bf2f(st.x), r1f = bf2f(st.y), r2f = bf2f(st.z), r3f = bf2f(st.w);
        dp[mr][nr >> 1] += r0f * ksumf[col0] + r1f * ksumf[col0 + 1] +
                           r2f * ksumf[col0 + 2] + r3f * ksumf[col0 + 3];
      }
    }
#pragma unroll
    for (int mr = 0; mr < 4; ++mr)
#pragma unroll
      for (int g = 0; g < 2; ++g) {
        dp[mr][g] += __shfl_xor(dp[mr][g], 16);
        dp[mr][g] += __shfl_xor(dp[mr][g], 32);
      }
    if (l < 16) {
#pragma unroll
      for (int mr = 0; mr < 4; ++mr) {
        int row = r0 + mr * 16 + l;
#pragma unroll
        for (int g = 0; g < 2; ++g)
          ma.rden[(size_t)row * 8 + ct * 4 + wn * 2 + g] = 1.f / (dp[mr][g] + 1e-8f);
      }
    }
  } else {
    // swapped layout: row = r0 + mr*16 + (l&15); cols = c0 + nr*16 + (l>>4)*4 + i
    const int rowl = l & 15, colq = (l >> 4) * 4;
#pragma unroll
    for (int mr = 0; mr < 4; ++mr) {
      int row = r0 + mr * 16 + rowl;
#pragma unroll
      for (int nr = 0; nr < 4; ++nr) {
        int col0 = c0 + nr * 16 + colq;
        if constexpr (MODE == GLOW) {
          if (col0 < 192) {
            float dl = ma.delayed[row];
            float4 wd = *(const float4*)(ma.wl_d + col0);
            float4 bp = *(const float4*)(ma.bl_p + col0);
            ushort4 st = {f2bf(acc[mr][nr][0] + dl * wd.x + bp.x),
                          f2bf(acc[mr][nr][1] + dl * wd.y + bp.y),
                          f2bf(acc[mr][nr][2] + dl * wd.z + bp.z),
                          f2bf(acc[mr][nr][3] + dl * wd.w + bp.w)};
            *(ushort4*)(ma.low + (size_t)row * 192 + col0) = st;
          }
        } else {  // GGEO
          u16* dst = ma.geopart + (size_t)bz * 4194304;
          ushort4 st = {f2bf(acc[mr][nr][0]), f2bf(acc[mr][nr][1]),
                        f2bf(acc[mr][nr][2]), f2bf(acc[mr][nr][3])};
          *(ushort4*)(dst + (size_t)row * 2048 + col0) = st;
        }
      }
    }
  }
}

// ---------------- gkv: per (head, 128-row chunk) compute k_h/v_h tile, then kv+ksum in-LDS ----------------
__global__ __launch_bounds__(256) void gkv_k(const u16* __restrict__ low,
                                             const u16* __restrict__ wqhTkv,
                                             const float* __restrict__ bqh,
                                             float* __restrict__ kvpart,
                                             float* __restrict__ kspart) {
  __shared__ __align__(16) u16 SH[17152];      // 34304 B
  u16* Al = SH;
  u16* Bl = SH + 128 * 64;
  u16* T  = SH;                                // [64][136] bf16, after barrier
  float* kvs = (float*)((char*)SH + 17408);    // [4][32][32]
  float* kss = (float*)((char*)SH + 17408 + 16384);  // [4][32]

  const int t = threadIdx.x;
  const int l = t & 63, w = t >> 6;

  int lin = blockIdx.x + 8 * blockIdx.y;
  int xcd = lin & 7, idx = lin >> 3;
  const int h = idx & 7;
  const int rt = xcd * 64 + (idx >> 3);
  const int b = rt >> 4, p = rt & 15;

  f4v acc[2][4] = {};

  for (int k0 = 0; k0 < 192; k0 += 64) {
    __syncthreads();
#pragma unroll
    for (int s = 0; s < 4; ++s) {
      int c = s * 256 + t;
      int r = c >> 3, cc = c & 7;
      int g = ((cc & 3) ^ ((r >> 1) & 3)) | ((cc & 4) ^ ((r & 1) << 2));
      gload16(low + (size_t)(rt * 128 + r) * 192 + k0 + g * 8,
              (char*)Al + (s * 4 + w) * 1024);
    }
#pragma unroll
    for (int s = 0; s < 2; ++s) {
      int c = s * 256 + t;
      int r = c >> 3, cc = c & 7;
      int g = ((cc & 3) ^ ((r >> 1) & 3)) | ((cc & 4) ^ ((r & 1) << 2));
      int wqrow = (r < 32) ? (h * 32 + r) : (256 + h * 32 + (r - 32));
      gload16(wqhTkv + (size_t)wqrow * 192 + k0 + g * 8,
              (char*)Bl + (s * 4 + w) * 1024);
    }
    __syncthreads();

#pragma unroll
    for (int kk = 0; kk < 64; kk += 32) {
      s8v fa[2], fb[4];
#pragma unroll
      for (int mr = 0; mr < 2; ++mr) {
        int ra = w * 32 + mr * 16 + (l & 15);
        int ch = ((l >> 4) ^ ((ra >> 1) & 3)) | ((kk >> 3) ^ ((ra & 1) << 2));
        fa[mr] = *(const s8v*)(Al + ra * 64 + ch * 8);
      }
#pragma unroll
      for (int nr = 0; nr < 4; ++nr) {
        int rb = nr * 16 + (l & 15);
        int cb = ((l >> 4) ^ ((rb >> 1) & 3)) | ((kk >> 3) ^ ((rb & 1) << 2));
        fb[nr] = *(const s8v*)(Bl + rb * 64 + cb * 8);
      }
#pragma unroll
      for (int mr = 0; mr < 2; ++mr)
#pragma unroll
        for (int nr = 0; nr < 4; ++nr)
          acc[mr][nr] = __builtin_amdgcn_mfma_f32_16x16x32_bf16(fa[mr], fb[nr], acc[mr][nr], 0, 0, 0);
    }
  }

  const int lr = (l >> 4) * 4, lc = l & 15;
  __syncthreads();
#pragma unroll
  for (int nr = 0; nr < 4; ++nr) {
    int cl = nr * 16 + lc;
    float bias = (cl < 32) ? bqh[256 + h * 32 + cl] : bqh[512 + h * 32 + (cl - 32)];
#pragma unroll
    for (int mr = 0; mr < 2; ++mr) {
      int n_l = w * 32 + mr * 16 + lr;
      float v0 = acc[mr][nr][0] + bias;
      float v1 = acc[mr][nr][1] + bias;
      float v2 = acc[mr][nr][2] + bias;
      float v3 = acc[mr][nr][3] + bias;
      if (cl < 32) {
        v0 = (v0 > 0.f) ? (v0 + 1.f) : __expf(v0);
        v1 = (v1 > 0.f) ? (v1 + 1.f) : __expf(v1);
        v2 = (v2 > 0.f) ? (v2 + 1.f) : __expf(v2);
        v3 = (v3 > 0.f) ? (v3 + 1.f) : __expf(v3);
      }
      ushort4 st = {f2bf(v0), f2bf(v1), f2bf(v2), f2bf(v3)};
      *(ushort4*)&T[cl * 136 + n_l] = st;
    }
  }
  __syncthreads();

  f4v acc2[2][2] = {};
  float ks[2] = {0.f, 0.f};
  {
    int koff = w * 32 + (l >> 4) * 8;
    s8v fa2[2], fb2[2];
#pragma unroll
    for (int mr = 0; mr < 2; ++mr)
      fa2[mr] = *(const s8v*)&T[(mr * 16 + (l & 15)) * 136 + koff];
#pragma unroll
    for (int nr = 0; nr < 2; ++nr)
      fb2[nr] = *(const s8v*)&T[(32 + nr * 16 + (l & 15)) * 136 + koff];
#pragma unroll
    for (int mr = 0; mr < 2; ++mr) {
      float sacc = 0.f;
#pragma unroll
      for (int j = 0; j < 8; ++j) sacc += bf2f((u16)fa2[mr][j]);
      ks[mr] = sacc;
    }
#pragma unroll
    for (int mr = 0; mr < 2; ++mr)
#pragma unroll
      for (int nr = 0; nr < 2; ++nr)
        acc2[mr][nr] = __builtin_amdgcn_mfma_f32_16x16x32_bf16(fa2[mr], fb2[nr], acc2[mr][nr], 0, 0, 0);
  }
  ks[0] += __shfl_xor(ks[0], 16); ks[0] += __shfl_xor(ks[0], 32);
  ks[1] += __shfl_xor(ks[1], 16); ks[1] += __shfl_xor(ks[1], 32);

#pragma unroll
  for (int mr = 0; mr < 2; ++mr)
#pragma unroll
    for (int nr = 0; nr < 2; ++nr)
#pragma unroll
      for (int i = 0; i < 4; ++i)
        kvs[(size_t)w * 1024 + (mr * 16 + (l >> 4) * 4 + i) * 32 + nr * 16 + (l & 15)] =
            acc2[mr][nr][i];
  if (l < 16) { kss[w * 32 + l] = ks[0]; kss[w * 32 + 16 + l] = ks[1]; }
  __syncthreads();

  float* kvp = kvpart + ((size_t)(p * 256 + b * 8 + h)) * 1024;
#pragma unroll
  for (int q = 0; q < 4; ++q) {
    int idx2 = q * 256 + t;
    kvp[idx2] = kvs[idx2] + kvs[1024 + idx2] + kvs[2048 + idx2] + kvs[3072 + idx2];
  }
  if (t < 32)
    kspart[((size_t)(p * 256 + b * 8 + h)) * 32 + t] =
        kss[t] + kss[32 + t] + kss[64 + t] + kss[96 + t];
}

// ---------------- GFIN: 64x256 tile, BK=64, 4 waves, LN aliased, 40KB LDS ----------------
__global__ __launch_bounds__(256) void gfin_k(const u16* __restrict__ qf,
                                              const float* __restrict__ rden,
                                              const u16* __restrict__ geopart,
                                              const u16* __restrict__ B2t,
                                              const float* __restrict__ cvec,
                                              const float* __restrict__ feats,
                                              const float* __restrict__ gamma,
                                              const float* __restrict__ beta,
                                              float* __restrict__ y) {
  __shared__ __align__(16) u16 Al[64 * 64];     // 8KB (doubles as LN buffers post-loop)
  __shared__ __align__(16) u16 Bl[256 * 64];    // 32KB
  float* LN1 = (float*)Al;                      // [4][64] aliased
  float* LN2 = LN1 + 256;

  const int t = threadIdx.x;
  const int l = t & 63, w = t >> 6;             // w = col quadrant (0..3)
  const int rt = blockIdx.x;
  const int b = rt >> 5;

  f4v acc[4][4] = {};

  for (int k0 = 0; k0 < 320; k0 += 64) {
    __syncthreads();
    // ---- A stage: 64 rows x 64 k ----
#pragma unroll
    for (int s = 0; s < 2; ++s) {
      int c = s * 256 + t;               // 0..511
      int r = c >> 3, cc = c & 7;
      int g = ((cc & 3) ^ ((r >> 1) & 3)) | ((cc & 4) ^ ((r & 1) << 2));
      int row = rt * 64 + r;
      int kg = k0 + g * 8;
      if (k0 < 256) {
        float sc = rden[(size_t)row * 8 + (kg >> 5)];
        s8v qv = *(const s8v*)(qf + (size_t)row * 256 + kg);
        uint4 qq = {pk2(bf2f((u16)qv[0]) * sc, bf2f((u16)qv[1]) * sc),
                    pk2(bf2f((u16)qv[2]) * sc, bf2f((u16)qv[3]) * sc),
                    pk2(bf2f((u16)qv[4]) * sc, bf2f((u16)qv[5]) * sc),
                    pk2(bf2f((u16)qv[6]) * sc, bf2f((u16)qv[7]) * sc)};
        *(uint4*)&Al[c * 8] = qq;
      } else {
        int n = row & 2047;
        const u16* gp = geopart + (size_t)n * 2048 + b * 64 + (kg - 256);
        s8v p0 = *(const s8v*)(gp);
        s8v p1 = *(const s8v*)(gp + 4194304);
        s8v p2 = *(const s8v*)(gp + 8388608);
        s8v p3 = *(const s8v*)(gp + 12582912);
        float vv[8];
#pragma unroll
        for (int j = 0; j < 8; ++j)
          vv[j] = bf2f((u16)p0[j]) + bf2f((u16)p1[j]) + bf2f((u16)p2[j]) + bf2f((u16)p3[j]);
        uint4 qq = {pk2(vv[0], vv[1]), pk2(vv[2], vv[3]), pk2(vv[4], vv[5]), pk2(vv[6], vv[7])};
        *(uint4*)&Al[c * 8] = qq;
      }
    }
    // ---- B stage: 256 rows x 64 k ----
#pragma unroll
    for (int s = 0; s < 8; ++s) {
      int c = s * 256 + t;               // 0..2047
      int r = c >> 3, cc = c & 7;
      int g = ((cc & 3) ^ ((r >> 1) & 3)) | ((cc & 4) ^ ((r & 1) << 2));
      gload16(B2t + ((size_t)b * 256 + r) * 320 + k0 + g * 8,
              (char*)Bl + (s * 4 + w) * 1024);
    }
    __syncthreads();

#pragma unroll
    for (int kk = 0; kk < 64; kk += 32) {
      s8v fa[4], fb[4];
#pragma unroll
      for (int mr = 0; mr < 4; ++mr) {
        int ra = mr * 16 + (l & 15);
        int ch = ((l >> 4) ^ ((ra >> 1) & 3)) | ((kk >> 3) ^ ((ra & 1) << 2));
        fa[mr] = *(const s8v*)(Al + ra * 64 + ch * 8);
      }
#pragma unroll
      for (int nr = 0; nr < 4; ++nr) {
        int rb = w * 64 + nr * 16 + (l & 15);
        int cb = ((l >> 4) ^ ((rb >> 1) & 3)) | ((kk >> 3) ^ ((rb & 1) << 2));
        fb[nr] = *(const s8v*)(Bl + rb * 64 + cb * 8);
      }
#pragma unroll
      for (int mr = 0; mr < 4; ++mr)
#pragma unroll
        for (int nr = 0; nr < 4; ++nr)
          acc[mr][nr] = __builtin_amdgcn_mfma_f32_16x16x32_bf16(fb[nr], fa[mr], acc[mr][nr], 0, 0, 0);
    }
  }

  // ---- epilogue: y = out + feats, LayerNorm over 256 cols ----
  const int rowl = l & 15, colq = (l >> 4) * 4;
  float s1v[4] = {0.f, 0.f, 0.f, 0.f}, s2v[4] = {0.f, 0.f, 0.f, 0.f};
#pragma unroll
  for (int mr = 0; mr < 4; ++mr) {
    int row = rt * 64 + mr * 16 + rowl;
#pragma unroll
    for (int nr = 0; nr < 4; ++nr) {
      int col0 = w * 64 + nr * 16 + colq;
      float4 cv = *(const float4*)(cvec + col0);
      float4 ft = *(const float4*)(feats + (size_t)row * 256 + col0);
      f4v vv = acc[mr][nr];
      vv[0] += cv.x + ft.x; vv[1] += cv.y + ft.y;
      vv[2] += cv.z + ft.z; vv[3] += cv.w + ft.w;
      acc[mr][nr] = vv;
      s1v[mr] += vv[0] + vv[1] + vv[2] + vv[3];
      s2v[mr] += vv[0] * vv[0] + vv[1] * vv[1] + vv[2] * vv[2] + vv[3] * vv[3];
    }
  }
#pragma unroll
  for (int mr = 0; mr < 4; ++mr) {
    s1v[mr] += __shfl_xor(s1v[mr], 16); s2v[mr] += __shfl_xor(s2v[mr], 16);
    s1v[mr] += __shfl_xor(s1v[mr], 32); s2v[mr] += __shfl_xor(s2v[mr], 32);
  }
  __syncthreads();                 // all Al fragment reads complete before aliasing
  if (l < 16) {
#pragma unroll
    for (int mr = 0; mr < 4; ++mr) {
      LN1[w * 64 + mr * 16 + l] = s1v[mr];
      LN2[w * 64 + mr * 16 + l] = s2v[mr];
    }
  }
  __syncthreads();
#pragma unroll
  for (int mr = 0; mr < 4; ++mr) {
    int rl = mr * 16 + rowl;
    int row = rt * 64 + rl;
    float s1 = LN1[rl] + LN1[64 + rl] + LN1[128 + rl] + LN1[192 + rl];
    float s2 = LN2[rl] + LN2[64 + rl] + LN2[128 + rl] + LN2[192 + rl];
    float mu = s1 * (1.f / 256.f);
    float var = s2 * (1.f / 256.f) - mu * mu;
    float rstd = rsqrtf(fmaxf(var, 0.f) + 1e-5f);
#pragma unroll
    for (int nr = 0; nr < 4; ++nr) {
      int col0 = w * 64 + nr * 16 + colq;
      float4 g4 = *(const float4*)(gamma + col0);
      float4 b4 = *(const float4*)(beta + col0);
      f4v vv = acc[mr][nr];
      float4 o;
      o.x = (vv[0] - mu) * rstd * g4.x + b4.x;
      o.y = (vv[1] - mu) * rstd * g4.y + b4.y;
      o.z = (vv[2] - mu) * rstd * g4.z + b4.z;
      o.w = (vv[3] - mu) * rstd * g4.w + b4.w;
      *(float4*)(y + (size_t)row * 256 + col0) = o;
    }
  }
}

// ---------------- M[b,h] = (1-gb) * kv[b,h] @ Wl_h (fp32 kvpart x16) ----------------
__global__ __launch_bounds__(64) void mmat_k(const float* __restrict__ kvpart,
                                             const float* __restrict__ wol,
                                             const float* __restrict__ geow,
                                             float* __restrict__ Mm) {
  const int bh = blockIdx.x;
  const int h = bh & 7, b = bh >> 3;
  const int c = threadIdx.x;
  __shared__ float kvs[32][32];
  for (int i = c; i < 1024; i += 64) {
    float s = 0.f;
#pragma unroll
    for (int p = 0; p < 16; ++p) s += kvpart[(size_t)(p * 256 + bh) * 1024 + i];
    kvs[i >> 5][i & 31] = s;
  }
  __syncthreads();
  float one_m = 1.f - 1.f / (1.f + __expf(-geow[0]));
  float acc[32];
#pragma unroll
  for (int d = 0; d < 32; ++d) acc[d] = 0.f;
  for (int e = 0; e < 32; ++e) {
    float w = wol[(size_t)(h * 32 + e) * 64 + c];
#pragma unroll
    for (int d = 0; d < 32; ++d) acc[d] = fmaf(kvs[d][e], w, acc[d]);
  }
  float* mp = Mm + (size_t)b * 16384 + (size_t)h * 32 * 64 + c;
#pragma unroll
  for (int d = 0; d < 32; ++d) mp[d * 64] = one_m * acc[d];
}

// ---------------- B2t[b][c][320] = [ (Mm[b]@Woh)^T ; gb*Woh^T ] ; cvec ----------------
__global__ __launch_bounds__(256) void bprep_k(const float* __restrict__ Mm,
                                               const float* __restrict__ woh,
                                               const float* __restrict__ bol,
                                               const float* __restrict__ boh,
                                               const float* __restrict__ geow,
                                               u16* __restrict__ B2t,
                                               float* __restrict__ cvec) {
  const int kt = blockIdx.x, b = blockIdx.y;   // kt<4 (64 k each)
  const int c = threadIdx.x;                   // 0..255
  __shared__ float Ms[64][64];
#pragma unroll
  for (int i = 0; i < 16; ++i) {
    int flat = c + i * 256;
    int kk = flat >> 6, e = flat & 63;
    Ms[kk][e] = Mm[(size_t)b * 16384 + (size_t)(kt * 64 + kk) * 64 + e];
  }
  __syncthreads();
  float wcol[64];
#pragma unroll
  for (int e = 0; e < 64; ++e) wcol[e] = woh[(size_t)e * 256 + c];
  u16* dst = B2t + ((size_t)b * 256 + c) * 320;
  for (int kk = 0; kk < 64; ++kk) {
    float s = 0.f;
#pragma unroll
    for (int e = 0; e < 64; ++e) s = fmaf(Ms[kk][e], wcol[e], s);
    dst[kt * 64 + kk] = f2bf(s);
  }
  if (kt == 0) {
    float gb = 1.f / (1.f + __expf(-geow[0]));
#pragma unroll
    for (int d = 0; d < 64; ++d) dst[256 + d] = f2bf(gb * wcol[d]);
    if (b == 0) {
      float s = boh[c];
#pragma unroll
      for (int d = 0; d < 64; ++d) s = fmaf(bol[d], wcol[d], s);
      cvec[c] = s;
    }
  }
}

// ---------------- host ----------------
extern "C" void kernel_launch(void* const* d_in, const int* in_sizes, int n_in,
                              void* d_out, int out_size, void* d_ws, size_t ws_size,
                              hipStream_t stream) {
  const float* x     = (const float*)d_in[0];
  const float* feats = (const float*)d_in[1];
  const float* dlog  = (const float*)d_in[2];
  const float* w_dp  = (const float*)d_in[3];
  const float* b_dp  = (const float*)d_in[4];
  const float* wql   = (const float*)d_in[5];
  const float* bql   = (const float*)d_in[6];
  const float* wqh   = (const float*)d_in[7];
  const float* bqh   = (const float*)d_in[8];
  const float* wol   = (const float*)d_in[9];
  const float* bol   = (const float*)d_in[10];
  const float* woh   = (const float*)d_in[11];
  const float* boh   = (const float*)d_in[12];
  const float* adj   = (const float*)d_in[13];
  const float* geow  = (const float*)d_in[14];
  const float* gamma = (const float*)d_in[15];
  const float* beta  = (const float*)d_in[16];

  char* ws = (char*)d_ws;
  // high-water 136,273,920 B (proven)
  constexpr size_t OFF_WLD   = 1024;
  constexpr size_t OFF_BLP   = 2048;
  constexpr size_t OFF_CVEC  = 4096;
  constexpr size_t OFF_CVL   = 5120;
  constexpr size_t OFF_DEL   = 8192;        // 256KB -> 270336
  constexpr size_t OFF_WQLT  = 270336;      // -> 401408
  constexpr size_t OFF_WQHT  = 401408;      // -> 696320
  constexpr size_t OFF_WVLT  = 696320;      // -> 745472
  constexpr size_t OFF_RDEN  = 876544;      // 2MB -> 2973696
  constexpr size_t OFF_MM    = 2973696;     // 2MB -> 5070848
  constexpr size_t OFF_B2T   = 5070848;     // 5MB -> 10313728 (< OFF_LOW)
  constexpr size_t OFF_LOW   = 10444800;    // 24MB [GLOW..GVP]
  constexpr size_t OFF_QF    = 35610624;    // 32MB [GQ..gfin]
  constexpr size_t OFF_KF    = 69165056;    // 32MB region
  constexpr size_t OFF_VPT   = OFF_KF;                 // 8MB [GVP..GGEO]
  constexpr size_t OFF_ADJB  = OFF_KF + 8388608;       // 8MB [cvtadj..GGEO]
  constexpr size_t OFF_V     = 102719488;   // 32MB region
  constexpr size_t OFF_KVP   = OFF_V;                  // 16MB fp32 [gkv..mmat]
  constexpr size_t OFF_KSP   = OFF_V + 16777216;       // 512KB [gkv..GQ]
  constexpr size_t OFF_GPART = OFF_V;                  // 4x8MB [GGEO..gfin] (after mmat/GQ)

  float* wl_d    = (float*)(ws + OFF_WLD);
  float* bl_p    = (float*)(ws + OFF_BLP);
  float* cvec    = (float*)(ws + OFF_CVEC);
  float* cvl     = (float*)(ws + OFF_CVL);
  float* delayed = (float*)(ws + OFF_DEL);
  float* kspart  = (float*)(ws + OFF_KSP);
  float* rden    = (float*)(ws + OFF_RDEN);
  float* Mm      = (float*)(ws + OFF_MM);
  float* kvpart  = (float*)(ws + OFF_KVP);
  u16* wqlT = (u16*)(ws + OFF_WQLT);
  u16* wqhT = (u16*)(ws + OFF_WQHT);
  u16* wvlT = (u16*)(ws + OFF_WVLT);
  u16* B2t  = (u16*)(ws + OFF_B2T);
  u16* adjb = (u16*)(ws + OFF_ADJB);

  MArgs ma{};
  ma.delayed = delayed; ma.wl_d = wl_d; ma.bl_p = bl_p; ma.bqh = bqh; ma.cvl = cvl;
  ma.adjb = adjb;
  ma.kspart = kspart; ma.rden = rden;
  ma.low = (u16*)(ws + OFF_LOW);
  ma.qf  = (u16*)(ws + OFF_QF);
  ma.vpt = (u16*)(ws + OFF_VPT);
  ma.geopart = (u16*)(ws + OFF_GPART);

  prep_all_k<<<1409, 256, 0, stream>>>(x, dlog, w_dp, b_dp, wql, bql, wqh, wol, bqh,
                                       wl_d, bl_p, delayed, wqlT, wqhT, wvlT, cvl);

  MArgs m0 = ma; m0.Af32 = feats; m0.Bt = wqlT;
  mgemm_k<GLOW><<<dim3(2, 512), 256, 0, stream>>>(m0);        // low (bf16)

  gkv_k<<<dim3(8, 512), 256, 0, stream>>>(ma.low, wqhT + (size_t)256 * 192, bqh,
                                          kvpart, kspart);    // kv + ksum partials

  MArgs m1 = ma; m1.A = ma.low; m1.Bt = wqhT;
  mgemm_k<GQ><<<dim3(2, 512), 256, 0, stream>>>(m1);          // qf (elu) + fused rden

  cvtadj_k<<<2048, 256, 0, stream>>>(adj, adjb);              // adj -> bf16
  mmat_k<<<256, 64, 0, stream>>>(kvpart, wol, geow, Mm);
  bprep_k<<<dim3(4, 32), 256, 0, stream>>>(Mm, woh, bol, boh, geow, B2t, cvec);

  MArgs m2 = ma; m2.A = ma.low; m2.Bt = wvlT;
  mgemm_k<GVP><<<dim3(1, 512), 256, 0, stream>>>(m2);         // vpt = (low@Wvl+cvl)^T bf16

  MArgs m3 = ma; m3.Bt = ma.vpt;
  mgemm_k<GGEO><<<dim3(16, 16, 4), 256, 0, stream>>>(m3);     // split-K=4 partials

  gfin_k<<<1024, 256, 0, stream>>>(ma.qf, rden, ma.geopart, B2t, cvec,
                                   feats, gamma, beta, (float*)d_out);
  (void)in_sizes; (void)n_in; (void)out_size; (void)ws_size;
}